// Round 8
// baseline (200.632 us; speedup 1.0000x reference)
//
#include <hip/hip_runtime.h>
#include <hip/hip_fp16.h>

#define BATCH 16
#define REG_BASE 196608   // out offset of reg[16]

// ---- ws layout ----
#define H_OFF      0        // floats: h[16][32]
#define MOM_OFF    512      // floats: mom[17][4] = {sx,sy,sz,s2}; idx16 = A
#define CROSS_OFF  580      // floats: cross[16]
#define CNT_OFF    596      // float-slot used as uint counter
#define STREAMH_B  4096     // byte offset: f16 rows [g][n][16 halves] (32 B each)
#define WS_BYTES   ((size_t)STREAMH_B + (size_t)4 * 2048 * 32)

#define CBLKS 2304          // 576 triangle tiles (256-i x 16-j) * 4 batch-groups

// half <-> float helpers (device)
__device__ __forceinline__ float h2f_lo(unsigned w) {
    unsigned short u = (unsigned short)(w & 0xffffu);
    _Float16 h; __builtin_memcpy(&h, &u, 2); return (float)h;
}
__device__ __forceinline__ float h2f_hi(unsigned w) {
    unsigned short u = (unsigned short)(w >> 16);
    _Float16 h; __builtin_memcpy(&h, &u, 2); return (float)h;
}
__device__ __forceinline__ void f16st(unsigned char* p, float f) {
    _Float16 h = (_Float16)f; __builtin_memcpy(p, &h, 2);
}

// ===========================================================================
// k_h: h[b][j] = relu(x_pos[b] . W1[j] + b1[j]); zero mom/cross/counter.
// grid (4 jg, 16 b), 256 thr: 8 units/block, 32 lanes/unit.
// ===========================================================================
__global__ __launch_bounds__(256) void k_h(
    const float* __restrict__ x, const float* __restrict__ W1,
    const float* __restrict__ b1, float* __restrict__ ws)
{
    const int jg = blockIdx.x, b = blockIdx.y;
    const int t = threadIdx.x;
    const int j = jg * 8 + (t >> 5);
    const int l = t & 31;

    if (jg == 0 && b == 0 && t < 85)   // mom(68) + cross(16) + counter(1)
        ws[MOM_OFF + t] = 0.f;

    const float4* xb4 = reinterpret_cast<const float4*>(x + (size_t)b * 12288);
    const float4* wj4 = reinterpret_cast<const float4*>(W1 + (size_t)j * 6144);
    float dot = 0.f;
    #pragma unroll 4
    for (int k = l; k < 1536; k += 32) {
        float4 a = xb4[k];
        float4 w = wj4[k];
        dot += a.x * w.x + a.y * w.y + a.z * w.z + a.w * w.w;
    }
    dot += __shfl_xor(dot, 1, 32);
    dot += __shfl_xor(dot, 2, 32);
    dot += __shfl_xor(dot, 4, 32);
    dot += __shfl_xor(dot, 8, 32);
    dot += __shfl_xor(dot, 16, 32);
    if (l == 0) ws[H_OFF + b * 32 + j] = fmaxf(dot + b1[j], 0.f);
}

// ===========================================================================
// k_transform: per-block z/R/T (redundant, cheap), X_t transform + softmax,
// pack f16 stream rows, f32 moments. grid (8 chunks, 17 b) — b==16 packs A.
// Row halves: [ax,ay,az,pad, p0x,p0y,p0z, p1x,p1y,p1z, p2x,p2y,p2z, p3x,p3y,p3z]
// ===========================================================================
__global__ __launch_bounds__(256) void k_transform(
    const float* __restrict__ x, const float* __restrict__ A,
    const float* __restrict__ W2, const float* __restrict__ b2,
    const float* __restrict__ center, const float* __restrict__ sz,
    float* __restrict__ out, float* __restrict__ ws)
{
    const int c = blockIdx.x, b = blockIdx.y;
    const int t = threadIdx.x;
    const int n = c * 256 + t;
    unsigned char* wb = (unsigned char*)ws;

    __shared__ float zs[3][3];
    __shared__ float Rl[3][9];
    __shared__ float Tl[3][3];

    float px, py, pz;
    if (b < BATCH) {
        if (t < 9) {
            const int s = t / 3, d = t % 3;
            const float* hb = ws + H_OFF + b * 32;
            const int row = s * 6 + 3 + d;
            float acc = b2[row];
            #pragma unroll
            for (int jj = 0; jj < 32; ++jj) acc += hb[jj] * W2[row * 32 + jj];
            zs[s][d] = tanhf(acc);
        }
        __syncthreads();
        if (t < 3) {
            const int s = t;
            const float PI = 3.14159265358979323846f;
            float c0 = cosf(PI * zs[s][0]), s0 = sinf(PI * zs[s][0]);
            float c1 = cosf(PI * zs[s][1]), s1 = sinf(PI * zs[s][1]);
            float c2 = cosf(PI * zs[s][2]), s2 = sinf(PI * zs[s][2]);
            float X[3][3] = {{c0, -s0, 0.f}, {s0, c0, 0.f}, {0.f, 0.f, 1.f}};
            float Y[3][3] = {{c1, 0.f, s1}, {0.f, 1.f, 0.f}, {-s1, 0.f, c1}};
            float Z[3][3] = {{1.f, 0.f, 0.f}, {0.f, c2, -s2}, {0.f, s2, c2}};
            float YZ[3][3], M[3][3];
            for (int m = 0; m < 3; ++m)
                for (int nn = 0; nn < 3; ++nn) {
                    float v = 0.f;
                    for (int k = 0; k < 3; ++k) v += Y[m][k] * Z[k][nn];
                    YZ[m][nn] = v;
                }
            for (int m = 0; m < 3; ++m)
                for (int nn = 0; nn < 3; ++nn) {
                    float v = 0.f;
                    for (int k = 0; k < 3; ++k) v += X[m][k] * YZ[k][nn];
                    M[m][nn] = v;
                    Rl[s][m * 3 + nn] = v;
                }
            for (int d = 0; d < 3; ++d)
                Tl[s][d] = zs[s][d] * sz[d] + center[d]
                         - (center[0] * M[0][d] + center[1] * M[1][d] + center[2] * M[2][d]);
        }
        __syncthreads();

        const float* xb = x + (size_t)b * 12288;
        px = xb[n]; py = xb[2048 + n]; pz = xb[4096 + n];

        // pack f16 stream slot for this batch
        {
            unsigned char* row = wb + STREAMH_B + ((size_t)((b >> 2) * 2048 + n)) * 32;
            const int q = b & 3;
            f16st(row + 2 * (4 + 3 * q), px);
            f16st(row + 2 * (5 + 3 * q), py);
            f16st(row + 2 * (6 + 3 * q), pz);
        }

        const int s = (n < 20) ? 0 : (n < 40) ? 1 : 2;
        float* ob = out + (size_t)b * 12288;
        #pragma unroll
        for (int d = 0; d < 3; ++d)
            ob[d * 2048 + n] = Rl[s][0 * 3 + d] * px + Rl[s][1 * 3 + d] * py
                             + Rl[s][2 * 3 + d] * pz + Tl[s][d];

        float c3 = xb[6144 + n], c4 = xb[8192 + n], c5 = xb[10240 + n];
        float mx = fmaxf(c3, fmaxf(c4, c5));
        float e3 = __expf(c3 - mx), e4 = __expf(c4 - mx), e5 = __expf(c5 - mx);
        float inv = 1.f / (e3 + e4 + e5);
        ob[6144 + n] = e3 * inv;
        ob[8192 + n] = e4 * inv;
        ob[10240 + n] = e5 * inv;
    } else {
        px = A[n]; py = A[2048 + n]; pz = A[4096 + n];
        #pragma unroll
        for (int g = 0; g < 4; ++g) {
            unsigned char* row = wb + STREAMH_B + ((size_t)(g * 2048 + n)) * 32;
            f16st(row + 0, px);
            f16st(row + 2, py);
            f16st(row + 4, pz);
        }
    }

    // f32 moments: {sx, sy, sz, s2}
    float v0 = px, v1 = py, v2 = pz, v3 = px * px + py * py + pz * pz;
    #pragma unroll
    for (int m = 1; m < 64; m <<= 1) {
        v0 += __shfl_xor(v0, m);
        v1 += __shfl_xor(v1, m);
        v2 += __shfl_xor(v2, m);
        v3 += __shfl_xor(v3, m);
    }
    __shared__ float wpart[4][4];
    const int w = t >> 6;
    if ((t & 63) == 0) {
        wpart[w][0] = v0; wpart[w][1] = v1; wpart[w][2] = v2; wpart[w][3] = v3;
    }
    __syncthreads();
    if (t < 4) {
        float s4 = wpart[0][t] + wpart[1][t] + wpart[2][t] + wpart[3][t];
        atomicAdd(&ws[MOM_OFF + b * 4 + t], s4);
    }
}

// ===========================================================================
// k_cross: cross[b] += sum_{i<j in tile} |a_i-a_j|*|p_i-p_j| for 4 batches.
// 576 triangle tiles (i-super 256 x j-tile 16) x 4 batch-groups = 2304 blocks
// -> 8 blocks/CU resident (32 waves/CU): latency fully hidden by TLP.
// j-rows are 32 B f16 in LDS (512 B stage) -> 2 wave-uniform ds_read_b128
// per 4 pair-slots; f32 math after in-register cvt; d2a shared across the
// 4 batches. Last block (device counter) finalizes reg[b].
// ===========================================================================
__global__ __launch_bounds__(256) void k_cross(
    float* __restrict__ ws, float* __restrict__ out)
{
    const int bx = blockIdx.x;
    const int g = bx / 576;
    int rem = bx % 576, s = 0;
    while (rem >= 128 - 16 * s) { rem -= 128 - 16 * s; ++s; }
    const int tj = 16 * s + rem;          // j-tile index in [16s, 128)
    const bool diag = (rem < 16);         // j-tile inside i-super's range
    const int t = threadIdx.x;
    const int i = s * 256 + t;
    const int jb = tj * 16;
    const int b0 = g * 4;

    unsigned char* wb = (unsigned char*)ws;

    // stage j-tile: 16 rows x 32 B = 512 B
    __shared__ uint4 jr[32];
    {
        const uint4* src = reinterpret_cast<const uint4*>(
            wb + STREAMH_B + (size_t)(g * 2048 + jb) * 32);
        if (t < 32) jr[t] = src[t];
    }

    // own i-row (per-lane, 32 B), convert once
    const uint4* irp = reinterpret_cast<const uint4*>(
        wb + STREAMH_B + (size_t)(g * 2048 + i) * 32);
    uint4 I0 = irp[0], I1 = irp[1];
    const float aix = h2f_lo(I0.x), aiy = h2f_hi(I0.x), aiz = h2f_lo(I0.y);
    const float p0x = h2f_lo(I0.z), p0y = h2f_hi(I0.z), p0z = h2f_lo(I0.w);
    const float p1x = h2f_hi(I0.w), p1y = h2f_lo(I1.x), p1z = h2f_hi(I1.x);
    const float p2x = h2f_lo(I1.y), p2y = h2f_hi(I1.y), p2z = h2f_lo(I1.z);
    const float p3x = h2f_hi(I1.z), p3y = h2f_lo(I1.w), p3z = h2f_hi(I1.w);

    __syncthreads();

    float a0 = 0.f, a1 = 0.f, a2 = 0.f, a3 = 0.f;

#define STEP(PRED)                                                           \
    {                                                                        \
        uint4 L = jr[2 * k], H = jr[2 * k + 1];                              \
        float vx = aix - h2f_lo(L.x);                                        \
        float vy = aiy - h2f_hi(L.x);                                        \
        float vz = aiz - h2f_lo(L.y);                                        \
        float d2a = fmaf(vx, vx, fmaf(vy, vy, vz * vz));                     \
        float u0x = p0x - h2f_lo(L.z), u0y = p0y - h2f_hi(L.z);              \
        float u0z = p0z - h2f_lo(L.w);                                       \
        float d20 = fmaf(u0x, u0x, fmaf(u0y, u0y, u0z * u0z));               \
        float u1x = p1x - h2f_hi(L.w), u1y = p1y - h2f_lo(H.x);              \
        float u1z = p1z - h2f_hi(H.x);                                       \
        float d21 = fmaf(u1x, u1x, fmaf(u1y, u1y, u1z * u1z));               \
        float u2x = p2x - h2f_lo(H.y), u2y = p2y - h2f_hi(H.y);              \
        float u2z = p2z - h2f_lo(H.z);                                       \
        float d22 = fmaf(u2x, u2x, fmaf(u2y, u2y, u2z * u2z));               \
        float u3x = p3x - h2f_hi(H.z), u3y = p3y - h2f_lo(H.w);              \
        float u3z = p3z - h2f_hi(H.w);                                       \
        float d23 = fmaf(u3x, u3x, fmaf(u3y, u3y, u3z * u3z));               \
        float s0 = __builtin_amdgcn_sqrtf(d20 * d2a);                        \
        float s1 = __builtin_amdgcn_sqrtf(d21 * d2a);                        \
        float s2 = __builtin_amdgcn_sqrtf(d22 * d2a);                        \
        float s3 = __builtin_amdgcn_sqrtf(d23 * d2a);                        \
        if (PRED) {                                                          \
            bool ok = (jb + k > i);                                          \
            s0 = ok ? s0 : 0.f; s1 = ok ? s1 : 0.f;                          \
            s2 = ok ? s2 : 0.f; s3 = ok ? s3 : 0.f;                          \
        }                                                                    \
        a0 += s0; a1 += s1; a2 += s2; a3 += s3;                              \
    }

    if (diag) {
        #pragma unroll 4
        for (int k = 0; k < 16; ++k) STEP(true)
    } else {
        #pragma unroll 4
        for (int k = 0; k < 16; ++k) STEP(false)
    }
#undef STEP

    #pragma unroll
    for (int m = 1; m < 64; m <<= 1) {
        a0 += __shfl_xor(a0, m);
        a1 += __shfl_xor(a1, m);
        a2 += __shfl_xor(a2, m);
        a3 += __shfl_xor(a3, m);
    }
    __shared__ float wsum[4][4];
    if ((t & 63) == 0) {
        const int w = t >> 6;
        wsum[w][0] = a0; wsum[w][1] = a1; wsum[w][2] = a2; wsum[w][3] = a3;
    }
    __syncthreads();
    if (t == 0) {
        #pragma unroll
        for (int q = 0; q < 4; ++q) {
            float sm = wsum[0][q] + wsum[1][q] + wsum[2][q] + wsum[3][q];
            atomicAdd(&ws[CROSS_OFF + b0 + q], sm);
        }
        __threadfence();
        unsigned old = atomicAdd(reinterpret_cast<unsigned*>(&ws[CNT_OFF]), 1u);
        if (old == CBLKS - 1) {
            __threadfence();
            const float* ma = ws + MOM_OFF + 16 * 4;
            float S2a = 2.f * (2048.f * ma[3] - (ma[0]*ma[0] + ma[1]*ma[1] + ma[2]*ma[2]));
            for (int b = 0; b < BATCH; ++b) {
                const float* mb = ws + MOM_OFF + b * 4;
                float S2x = 2.f * (2048.f * mb[3] - (mb[0]*mb[0] + mb[1]*mb[1] + mb[2]*mb[2]));
                float cr = atomicAdd(&ws[CROSS_OFF + b], 0.f);
                out[REG_BASE + b] = sqrtf(fmaxf(S2a + S2x - 4.f * cr, 0.f));
            }
        }
    }
}

// ===========================================================================
// FALLBACK PATH (round-3 proven kernels; used only if ws too small)
// ===========================================================================
__global__ __launch_bounds__(256) void k_mlp_fb(
    const float* __restrict__ x, const float* __restrict__ W1,
    const float* __restrict__ b1, const float* __restrict__ W2,
    const float* __restrict__ b2, const float* __restrict__ center,
    const float* __restrict__ sz, float* __restrict__ out)
{
    const int b = blockIdx.x;
    const int t = threadIdx.x;
    __shared__ float hbuf[32];
    __shared__ float zbuf[18];
    __shared__ float Rl[3][9];
    __shared__ float Tl[3][3];
    {
        const int j = t >> 3;
        const int l = t & 7;
        const float4* xb4 = reinterpret_cast<const float4*>(x + (size_t)b * 12288);
        const float4* wj4 = reinterpret_cast<const float4*>(W1 + (size_t)j * 6144);
        float dot = 0.f;
        #pragma unroll 4
        for (int k = l; k < 1536; k += 8) {
            float4 a = xb4[k];
            float4 w = wj4[k];
            dot += a.x * w.x + a.y * w.y + a.z * w.z + a.w * w.w;
        }
        dot += __shfl_xor(dot, 1);
        dot += __shfl_xor(dot, 2);
        dot += __shfl_xor(dot, 4);
        if (l == 0) hbuf[j] = fmaxf(dot + b1[j], 0.f);
    }
    if (t == 0) out[REG_BASE + b] = 0.f;
    __syncthreads();
    if (t < 18) {
        float s = b2[t];
        #pragma unroll
        for (int j = 0; j < 32; ++j) s += hbuf[j] * W2[t * 32 + j];
        zbuf[t] = tanhf(s);
    }
    __syncthreads();
    if (t < 3) {
        const int s = t;
        const float PI = 3.14159265358979323846f;
        float a0 = PI * zbuf[s * 6 + 3], a1 = PI * zbuf[s * 6 + 4], a2 = PI * zbuf[s * 6 + 5];
        float c0 = cosf(a0), s0 = sinf(a0);
        float c1 = cosf(a1), s1 = sinf(a1);
        float c2 = cosf(a2), s2 = sinf(a2);
        float X[3][3] = {{c0, -s0, 0.f}, {s0, c0, 0.f}, {0.f, 0.f, 1.f}};
        float Y[3][3] = {{c1, 0.f, s1}, {0.f, 1.f, 0.f}, {-s1, 0.f, c1}};
        float Z[3][3] = {{1.f, 0.f, 0.f}, {0.f, c2, -s2}, {0.f, s2, c2}};
        float YZ[3][3], M[3][3];
        for (int m = 0; m < 3; ++m)
            for (int n = 0; n < 3; ++n) {
                float v = 0.f;
                for (int k = 0; k < 3; ++k) v += Y[m][k] * Z[k][n];
                YZ[m][n] = v;
            }
        for (int m = 0; m < 3; ++m)
            for (int n = 0; n < 3; ++n) {
                float v = 0.f;
                for (int k = 0; k < 3; ++k) v += X[m][k] * YZ[k][n];
                M[m][n] = v;
                Rl[s][m * 3 + n] = v;
            }
        for (int sd = 0; sd < 3; ++sd)
            Tl[s][sd] = zbuf[s * 6 + 3 + sd] * sz[sd] + center[sd]
                      - (center[0] * M[0][sd] + center[1] * M[1][sd] + center[2] * M[2][sd]);
    }
    __syncthreads();
    const float* xb = x + (size_t)b * 12288;
    float* ob = out + (size_t)b * 12288;
    for (int n = t; n < 2048; n += 256) {
        float px = xb[n], py = xb[2048 + n], pz = xb[4096 + n];
        int s = (n < 20) ? 0 : (n < 40) ? 1 : 2;
        #pragma unroll
        for (int td = 0; td < 3; ++td)
            ob[td * 2048 + n] = Rl[s][0 * 3 + td] * px + Rl[s][1 * 3 + td] * py
                              + Rl[s][2 * 3 + td] * pz + Tl[s][td];
        float c3 = xb[6144 + n], c4 = xb[8192 + n], c5 = xb[10240 + n];
        float mx = fmaxf(c3, fmaxf(c4, c5));
        float e3 = __expf(c3 - mx), e4 = __expf(c4 - mx), e5 = __expf(c5 - mx);
        float inv = 1.f / (e3 + e4 + e5);
        ob[6144 + n] = e3 * inv;
        ob[8192 + n] = e4 * inv;
        ob[10240 + n] = e5 * inv;
    }
}

__global__ __launch_bounds__(256) void k_reg_fb(
    const float* __restrict__ x, const float* __restrict__ A,
    float* __restrict__ out)
{
    const int p = blockIdx.x;
    const int b = blockIdx.y;
    int ci = 0, rem = p;
    while (rem >= 8 - ci) { rem -= 8 - ci; ++ci; }
    const int cj = ci + rem;
    const int t = threadIdx.x;
    __shared__ float4 pj[256];
    __shared__ float4 aj[256];
    const float* xb = x + (size_t)b * 12288;
    {
        int j = cj * 256 + t;
        pj[t] = make_float4(xb[j], xb[2048 + j], xb[4096 + j], 0.f);
        aj[t] = make_float4(A[j], A[2048 + j], A[4096 + j], 0.f);
    }
    __syncthreads();
    const int i = ci * 256 + t;
    const float pix = xb[i], piy = xb[2048 + i], piz = xb[4096 + i];
    const float aix = A[i], aiy = A[2048 + i], aiz = A[4096 + i];
    const int jbase = cj * 256;
    float acc = 0.f;
    #pragma unroll 4
    for (int jj = 0; jj < 256; ++jj) {
        float4 P = pj[jj];
        float4 Q = aj[jj];
        float dx0 = pix - P.x, dy0 = piy - P.y, dz0 = piz - P.z;
        float dxv = sqrtf(dx0 * dx0 + dy0 * dy0 + dz0 * dz0);
        float da0 = aix - Q.x, da1 = aiy - Q.y, da2 = aiz - Q.z;
        float dav = sqrtf(da0 * da0 + da1 * da1 + da2 * da2);
        float d = dav - dxv;
        float dd = (jbase + jj > i) ? d : 0.f;
        acc = fmaf(dd, dd, acc);
    }
    #pragma unroll
    for (int m = 1; m < 64; m <<= 1) acc += __shfl_xor(acc, m);
    __shared__ float wsum[4];
    if ((t & 63) == 0) wsum[t >> 6] = acc;
    __syncthreads();
    if (t == 0) atomicAdd(&out[REG_BASE + b], wsum[0] + wsum[1] + wsum[2] + wsum[3]);
}

__global__ void k_final_fb(float* __restrict__ out)
{
    int b = threadIdx.x;
    if (b < BATCH) out[REG_BASE + b] = sqrtf(2.f * out[REG_BASE + b]);
}

// ===========================================================================
extern "C" void kernel_launch(void* const* d_in, const int* in_sizes, int n_in,
                              void* d_out, int out_size, void* d_ws, size_t ws_size,
                              hipStream_t stream) {
    (void)in_sizes; (void)n_in; (void)out_size;
    const float* x      = (const float*)d_in[0];
    const float* W1     = (const float*)d_in[1];
    const float* b1     = (const float*)d_in[2];
    const float* W2     = (const float*)d_in[3];
    const float* b2     = (const float*)d_in[4];
    const float* A      = (const float*)d_in[5];
    const float* center = (const float*)d_in[6];
    const float* sz     = (const float*)d_in[7];
    float* out = (float*)d_out;
    float* ws  = (float*)d_ws;

    if (ws_size >= WS_BYTES) {
        k_h<<<dim3(4, 16), 256, 0, stream>>>(x, W1, b1, ws);
        k_transform<<<dim3(8, 17), 256, 0, stream>>>(x, A, W2, b2, center, sz, out, ws);
        k_cross<<<CBLKS, 256, 0, stream>>>(ws, out);
    } else {
        k_mlp_fb<<<BATCH, 256, 0, stream>>>(x, W1, b1, W2, b2, center, sz, out);
        k_reg_fb<<<dim3(36, 16), 256, 0, stream>>>(x, A, out);
        k_final_fb<<<1, 64, 0, stream>>>(out);
    }
}

// Round 9
// 101.526 us; speedup vs baseline: 1.9762x; 1.9762x over previous
//
#include <hip/hip_runtime.h>
#include <hip/hip_fp16.h>

#define BATCH 16
#define REG_BASE 196608   // out offset of reg[16]

// ---- ws layout ----
#define H_OFF      0        // floats: h[16][32]
#define MOM_OFF    512      // floats: mom[17][4] = {sx,sy,sz,s2}; idx16 = A
#define PART_OFF   640      // floats: part[(g*288+tile)*4 + q], 4608 floats
#define STREAMH_B  32768    // byte offset: f16 rows [g][n][16 halves] (32 B each)
#define WS_BYTES   ((size_t)STREAMH_B + (size_t)4 * 2048 * 32)

#define NTILES 288          // triangle tiles (i-super 256 x j-tile 32)
#define CBLKS  (NTILES * 4) // * 4 batch-groups = 1152 blocks

// half <-> float helpers (device)
__device__ __forceinline__ float h2f_lo(unsigned w) {
    unsigned short u = (unsigned short)(w & 0xffffu);
    _Float16 h; __builtin_memcpy(&h, &u, 2); return (float)h;
}
__device__ __forceinline__ float h2f_hi(unsigned w) {
    unsigned short u = (unsigned short)(w >> 16);
    _Float16 h; __builtin_memcpy(&h, &u, 2); return (float)h;
}
__device__ __forceinline__ void f16st(unsigned char* p, float f) {
    _Float16 h = (_Float16)f; __builtin_memcpy(p, &h, 2);
}

// ===========================================================================
// k_h: h[b][j] = relu(x_pos[b] . W1[j] + b1[j]); zero moments.
// grid (4 jg, 16 b), 256 thr: 8 units/block, 32 lanes/unit.
// ===========================================================================
__global__ __launch_bounds__(256) void k_h(
    const float* __restrict__ x, const float* __restrict__ W1,
    const float* __restrict__ b1, float* __restrict__ ws)
{
    const int jg = blockIdx.x, b = blockIdx.y;
    const int t = threadIdx.x;
    const int j = jg * 8 + (t >> 5);
    const int l = t & 31;

    if (jg == 0 && b == 0 && t < 68)   // mom(68)
        ws[MOM_OFF + t] = 0.f;

    const float4* xb4 = reinterpret_cast<const float4*>(x + (size_t)b * 12288);
    const float4* wj4 = reinterpret_cast<const float4*>(W1 + (size_t)j * 6144);
    float dot = 0.f;
    #pragma unroll 4
    for (int k = l; k < 1536; k += 32) {
        float4 a = xb4[k];
        float4 w = wj4[k];
        dot += a.x * w.x + a.y * w.y + a.z * w.z + a.w * w.w;
    }
    dot += __shfl_xor(dot, 1, 32);
    dot += __shfl_xor(dot, 2, 32);
    dot += __shfl_xor(dot, 4, 32);
    dot += __shfl_xor(dot, 8, 32);
    dot += __shfl_xor(dot, 16, 32);
    if (l == 0) ws[H_OFF + b * 32 + j] = fmaxf(dot + b1[j], 0.f);
}

// ===========================================================================
// k_transform: per-block z/R/T (redundant, cheap), X_t transform + softmax,
// pack f16 stream rows, f32 moments. grid (8 chunks, 17 b) — b==16 packs A.
// Row halves: [ax,ay,az,pad, p0x,p0y,p0z, p1x,p1y,p1z, p2x,p2y,p2z, p3x,p3y,p3z]
// ===========================================================================
__global__ __launch_bounds__(256) void k_transform(
    const float* __restrict__ x, const float* __restrict__ A,
    const float* __restrict__ W2, const float* __restrict__ b2,
    const float* __restrict__ center, const float* __restrict__ sz,
    float* __restrict__ out, float* __restrict__ ws)
{
    const int c = blockIdx.x, b = blockIdx.y;
    const int t = threadIdx.x;
    const int n = c * 256 + t;
    unsigned char* wb = (unsigned char*)ws;

    __shared__ float zs[3][3];
    __shared__ float Rl[3][9];
    __shared__ float Tl[3][3];

    float px, py, pz;
    if (b < BATCH) {
        if (t < 9) {
            const int s = t / 3, d = t % 3;
            const float* hb = ws + H_OFF + b * 32;
            const int row = s * 6 + 3 + d;
            float acc = b2[row];
            #pragma unroll
            for (int jj = 0; jj < 32; ++jj) acc += hb[jj] * W2[row * 32 + jj];
            zs[s][d] = tanhf(acc);
        }
        __syncthreads();
        if (t < 3) {
            const int s = t;
            const float PI = 3.14159265358979323846f;
            float c0 = cosf(PI * zs[s][0]), s0 = sinf(PI * zs[s][0]);
            float c1 = cosf(PI * zs[s][1]), s1 = sinf(PI * zs[s][1]);
            float c2 = cosf(PI * zs[s][2]), s2 = sinf(PI * zs[s][2]);
            float X[3][3] = {{c0, -s0, 0.f}, {s0, c0, 0.f}, {0.f, 0.f, 1.f}};
            float Y[3][3] = {{c1, 0.f, s1}, {0.f, 1.f, 0.f}, {-s1, 0.f, c1}};
            float Z[3][3] = {{1.f, 0.f, 0.f}, {0.f, c2, -s2}, {0.f, s2, c2}};
            float YZ[3][3], M[3][3];
            for (int m = 0; m < 3; ++m)
                for (int nn = 0; nn < 3; ++nn) {
                    float v = 0.f;
                    for (int k = 0; k < 3; ++k) v += Y[m][k] * Z[k][nn];
                    YZ[m][nn] = v;
                }
            for (int m = 0; m < 3; ++m)
                for (int nn = 0; nn < 3; ++nn) {
                    float v = 0.f;
                    for (int k = 0; k < 3; ++k) v += X[m][k] * YZ[k][nn];
                    M[m][nn] = v;
                    Rl[s][m * 3 + nn] = v;
                }
            for (int d = 0; d < 3; ++d)
                Tl[s][d] = zs[s][d] * sz[d] + center[d]
                         - (center[0] * M[0][d] + center[1] * M[1][d] + center[2] * M[2][d]);
        }
        __syncthreads();

        const float* xb = x + (size_t)b * 12288;
        px = xb[n]; py = xb[2048 + n]; pz = xb[4096 + n];

        // pack f16 stream slot for this batch
        {
            unsigned char* row = wb + STREAMH_B + ((size_t)((b >> 2) * 2048 + n)) * 32;
            const int q = b & 3;
            f16st(row + 2 * (4 + 3 * q), px);
            f16st(row + 2 * (5 + 3 * q), py);
            f16st(row + 2 * (6 + 3 * q), pz);
        }

        const int s = (n < 20) ? 0 : (n < 40) ? 1 : 2;
        float* ob = out + (size_t)b * 12288;
        #pragma unroll
        for (int d = 0; d < 3; ++d)
            ob[d * 2048 + n] = Rl[s][0 * 3 + d] * px + Rl[s][1 * 3 + d] * py
                             + Rl[s][2 * 3 + d] * pz + Tl[s][d];

        float c3 = xb[6144 + n], c4 = xb[8192 + n], c5 = xb[10240 + n];
        float mx = fmaxf(c3, fmaxf(c4, c5));
        float e3 = __expf(c3 - mx), e4 = __expf(c4 - mx), e5 = __expf(c5 - mx);
        float inv = 1.f / (e3 + e4 + e5);
        ob[6144 + n] = e3 * inv;
        ob[8192 + n] = e4 * inv;
        ob[10240 + n] = e5 * inv;
    } else {
        px = A[n]; py = A[2048 + n]; pz = A[4096 + n];
        #pragma unroll
        for (int g = 0; g < 4; ++g) {
            unsigned char* row = wb + STREAMH_B + ((size_t)(g * 2048 + n)) * 32;
            f16st(row + 0, px);
            f16st(row + 2, py);
            f16st(row + 4, pz);
        }
    }

    // f32 moments: {sx, sy, sz, s2}
    float v0 = px, v1 = py, v2 = pz, v3 = px * px + py * py + pz * pz;
    #pragma unroll
    for (int m = 1; m < 64; m <<= 1) {
        v0 += __shfl_xor(v0, m);
        v1 += __shfl_xor(v1, m);
        v2 += __shfl_xor(v2, m);
        v3 += __shfl_xor(v3, m);
    }
    __shared__ float wpart[4][4];
    const int w = t >> 6;
    if ((t & 63) == 0) {
        wpart[w][0] = v0; wpart[w][1] = v1; wpart[w][2] = v2; wpart[w][3] = v3;
    }
    __syncthreads();
    if (t < 4) {
        float s4 = wpart[0][t] + wpart[1][t] + wpart[2][t] + wpart[3][t];
        atomicAdd(&ws[MOM_OFF + b * 4 + t], s4);
    }
}

// ===========================================================================
// k_cross: partial[g][tile][q] = sum_{i<j in tile} |a_i-a_j|*|p_i-p_j|
// for the 4 batches q of group g. 288 triangle tiles (i-super 256 x j-tile
// 32) x 4 groups = 1152 blocks. j-rows (32 B f16) staged in LDS (1 KB),
// broadcast via wave-uniform ds_read_b128; f32 math after in-register cvt;
// d2a shared across the 4 batches. NO atomics, NO fences — each block does
// one plain float4 store to its private partial slot (Guideline 12: the
// per-block same-line atomic+fence chain was serializing r5-r8 at ~60ns/blk).
// ===========================================================================
__global__ __launch_bounds__(256) void k_cross(
    float* __restrict__ ws, float* __restrict__ out)
{
    const int bx = blockIdx.x;
    const int g = bx / NTILES;
    const int tile = bx % NTILES;
    int rem = tile, s = 0;
    while (rem >= 64 - 8 * s) { rem -= 64 - 8 * s; ++s; }
    const int tj = 8 * s + rem;           // j-tile index in [8s, 64)
    const bool diag = (rem < 8);          // j-tile inside i-super's range
    const int t = threadIdx.x;
    const int i = s * 256 + t;
    const int jb = tj * 32;

    unsigned char* wb = (unsigned char*)ws;

    // stage j-tile: 32 rows x 32 B = 1 KB
    __shared__ uint4 jr[64];
    {
        const uint4* src = reinterpret_cast<const uint4*>(
            wb + STREAMH_B + (size_t)(g * 2048 + jb) * 32);
        if (t < 64) jr[t] = src[t];
    }

    // own i-row (per-lane, 32 B), convert once
    const uint4* irp = reinterpret_cast<const uint4*>(
        wb + STREAMH_B + (size_t)(g * 2048 + i) * 32);
    uint4 I0 = irp[0], I1 = irp[1];
    const float aix = h2f_lo(I0.x), aiy = h2f_hi(I0.x), aiz = h2f_lo(I0.y);
    const float p0x = h2f_lo(I0.z), p0y = h2f_hi(I0.z), p0z = h2f_lo(I0.w);
    const float p1x = h2f_hi(I0.w), p1y = h2f_lo(I1.x), p1z = h2f_hi(I1.x);
    const float p2x = h2f_lo(I1.y), p2y = h2f_hi(I1.y), p2z = h2f_lo(I1.z);
    const float p3x = h2f_hi(I1.z), p3y = h2f_lo(I1.w), p3z = h2f_hi(I1.w);

    __syncthreads();

    float a0 = 0.f, a1 = 0.f, a2 = 0.f, a3 = 0.f;

#define STEP(PRED)                                                           \
    {                                                                        \
        uint4 L = jr[2 * k], H = jr[2 * k + 1];                              \
        float vx = aix - h2f_lo(L.x);                                        \
        float vy = aiy - h2f_hi(L.x);                                        \
        float vz = aiz - h2f_lo(L.y);                                        \
        float d2a = fmaf(vx, vx, fmaf(vy, vy, vz * vz));                     \
        float u0x = p0x - h2f_lo(L.z), u0y = p0y - h2f_hi(L.z);              \
        float u0z = p0z - h2f_lo(L.w);                                       \
        float d20 = fmaf(u0x, u0x, fmaf(u0y, u0y, u0z * u0z));               \
        float u1x = p1x - h2f_hi(L.w), u1y = p1y - h2f_lo(H.x);              \
        float u1z = p1z - h2f_hi(H.x);                                       \
        float d21 = fmaf(u1x, u1x, fmaf(u1y, u1y, u1z * u1z));               \
        float u2x = p2x - h2f_lo(H.y), u2y = p2y - h2f_hi(H.y);              \
        float u2z = p2z - h2f_lo(H.z);                                       \
        float d22 = fmaf(u2x, u2x, fmaf(u2y, u2y, u2z * u2z));               \
        float u3x = p3x - h2f_hi(H.z), u3y = p3y - h2f_lo(H.w);              \
        float u3z = p3z - h2f_hi(H.w);                                       \
        float d23 = fmaf(u3x, u3x, fmaf(u3y, u3y, u3z * u3z));               \
        float s0 = __builtin_amdgcn_sqrtf(d20 * d2a);                        \
        float s1 = __builtin_amdgcn_sqrtf(d21 * d2a);                        \
        float s2 = __builtin_amdgcn_sqrtf(d22 * d2a);                        \
        float s3 = __builtin_amdgcn_sqrtf(d23 * d2a);                        \
        if (PRED) {                                                          \
            bool ok = (jb + k > i);                                          \
            s0 = ok ? s0 : 0.f; s1 = ok ? s1 : 0.f;                          \
            s2 = ok ? s2 : 0.f; s3 = ok ? s3 : 0.f;                          \
        }                                                                    \
        a0 += s0; a1 += s1; a2 += s2; a3 += s3;                              \
    }

    if (diag) {
        #pragma unroll 4
        for (int k = 0; k < 32; ++k) STEP(true)
    } else {
        #pragma unroll 4
        for (int k = 0; k < 32; ++k) STEP(false)
    }
#undef STEP

    #pragma unroll
    for (int m = 1; m < 64; m <<= 1) {
        a0 += __shfl_xor(a0, m);
        a1 += __shfl_xor(a1, m);
        a2 += __shfl_xor(a2, m);
        a3 += __shfl_xor(a3, m);
    }
    __shared__ float wsum[4][4];
    if ((t & 63) == 0) {
        const int w = t >> 6;
        wsum[w][0] = a0; wsum[w][1] = a1; wsum[w][2] = a2; wsum[w][3] = a3;
    }
    __syncthreads();
    if (t == 0) {
        float4 v;
        v.x = wsum[0][0] + wsum[1][0] + wsum[2][0] + wsum[3][0];
        v.y = wsum[0][1] + wsum[1][1] + wsum[2][1] + wsum[3][1];
        v.z = wsum[0][2] + wsum[1][2] + wsum[2][2] + wsum[3][2];
        v.w = wsum[0][3] + wsum[1][3] + wsum[2][3] + wsum[3][3];
        *reinterpret_cast<float4*>(&ws[PART_OFF + (size_t)(g * NTILES + tile) * 4]) = v;
    }
    (void)out;
}

// ===========================================================================
// k_final: reg[b] = sqrt(S2a + S2x[b] - 4*sum(part[b])). 16 blocks.
// ===========================================================================
__global__ __launch_bounds__(256) void k_final(
    const float* __restrict__ ws, float* __restrict__ out)
{
    const int b = blockIdx.x;           // 0..15
    const int g = b >> 2, q = b & 3;
    const int t = threadIdx.x;
    float s = 0.f;
    for (int k = t; k < NTILES; k += 256)
        s += ws[PART_OFF + (size_t)(g * NTILES + k) * 4 + q];
    #pragma unroll
    for (int m = 1; m < 64; m <<= 1) s += __shfl_xor(s, m);
    __shared__ float wsum[4];
    if ((t & 63) == 0) wsum[t >> 6] = s;
    __syncthreads();
    if (t == 0) {
        float cr = wsum[0] + wsum[1] + wsum[2] + wsum[3];
        const float* ma = ws + MOM_OFF + 16 * 4;
        const float* mb = ws + MOM_OFF + b * 4;
        float S2a = 2.f * (2048.f * ma[3] - (ma[0]*ma[0] + ma[1]*ma[1] + ma[2]*ma[2]));
        float S2x = 2.f * (2048.f * mb[3] - (mb[0]*mb[0] + mb[1]*mb[1] + mb[2]*mb[2]));
        out[REG_BASE + b] = sqrtf(fmaxf(S2a + S2x - 4.f * cr, 0.f));
    }
}

// ===========================================================================
// FALLBACK PATH (round-3 proven kernels; used only if ws too small)
// ===========================================================================
__global__ __launch_bounds__(256) void k_mlp_fb(
    const float* __restrict__ x, const float* __restrict__ W1,
    const float* __restrict__ b1, const float* __restrict__ W2,
    const float* __restrict__ b2, const float* __restrict__ center,
    const float* __restrict__ sz, float* __restrict__ out)
{
    const int b = blockIdx.x;
    const int t = threadIdx.x;
    __shared__ float hbuf[32];
    __shared__ float zbuf[18];
    __shared__ float Rl[3][9];
    __shared__ float Tl[3][3];
    {
        const int j = t >> 3;
        const int l = t & 7;
        const float4* xb4 = reinterpret_cast<const float4*>(x + (size_t)b * 12288);
        const float4* wj4 = reinterpret_cast<const float4*>(W1 + (size_t)j * 6144);
        float dot = 0.f;
        #pragma unroll 4
        for (int k = l; k < 1536; k += 8) {
            float4 a = xb4[k];
            float4 w = wj4[k];
            dot += a.x * w.x + a.y * w.y + a.z * w.z + a.w * w.w;
        }
        dot += __shfl_xor(dot, 1);
        dot += __shfl_xor(dot, 2);
        dot += __shfl_xor(dot, 4);
        if (l == 0) hbuf[j] = fmaxf(dot + b1[j], 0.f);
    }
    if (t == 0) out[REG_BASE + b] = 0.f;
    __syncthreads();
    if (t < 18) {
        float s = b2[t];
        #pragma unroll
        for (int j = 0; j < 32; ++j) s += hbuf[j] * W2[t * 32 + j];
        zbuf[t] = tanhf(s);
    }
    __syncthreads();
    if (t < 3) {
        const int s = t;
        const float PI = 3.14159265358979323846f;
        float a0 = PI * zbuf[s * 6 + 3], a1 = PI * zbuf[s * 6 + 4], a2 = PI * zbuf[s * 6 + 5];
        float c0 = cosf(a0), s0 = sinf(a0);
        float c1 = cosf(a1), s1 = sinf(a1);
        float c2 = cosf(a2), s2 = sinf(a2);
        float X[3][3] = {{c0, -s0, 0.f}, {s0, c0, 0.f}, {0.f, 0.f, 1.f}};
        float Y[3][3] = {{c1, 0.f, s1}, {0.f, 1.f, 0.f}, {-s1, 0.f, c1}};
        float Z[3][3] = {{1.f, 0.f, 0.f}, {0.f, c2, -s2}, {0.f, s2, c2}};
        float YZ[3][3], M[3][3];
        for (int m = 0; m < 3; ++m)
            for (int n = 0; n < 3; ++n) {
                float v = 0.f;
                for (int k = 0; k < 3; ++k) v += Y[m][k] * Z[k][n];
                YZ[m][n] = v;
            }
        for (int m = 0; m < 3; ++m)
            for (int n = 0; n < 3; ++n) {
                float v = 0.f;
                for (int k = 0; k < 3; ++k) v += X[m][k] * YZ[k][n];
                M[m][n] = v;
                Rl[s][m * 3 + n] = v;
            }
        for (int sd = 0; sd < 3; ++sd)
            Tl[s][sd] = zbuf[s * 6 + 3 + sd] * sz[sd] + center[sd]
                      - (center[0] * M[0][sd] + center[1] * M[1][sd] + center[2] * M[2][sd]);
    }
    __syncthreads();
    const float* xb = x + (size_t)b * 12288;
    float* ob = out + (size_t)b * 12288;
    for (int n = t; n < 2048; n += 256) {
        float px = xb[n], py = xb[2048 + n], pz = xb[4096 + n];
        int s = (n < 20) ? 0 : (n < 40) ? 1 : 2;
        #pragma unroll
        for (int td = 0; td < 3; ++td)
            ob[td * 2048 + n] = Rl[s][0 * 3 + td] * px + Rl[s][1 * 3 + td] * py
                              + Rl[s][2 * 3 + td] * pz + Tl[s][td];
        float c3 = xb[6144 + n], c4 = xb[8192 + n], c5 = xb[10240 + n];
        float mx = fmaxf(c3, fmaxf(c4, c5));
        float e3 = __expf(c3 - mx), e4 = __expf(c4 - mx), e5 = __expf(c5 - mx);
        float inv = 1.f / (e3 + e4 + e5);
        ob[6144 + n] = e3 * inv;
        ob[8192 + n] = e4 * inv;
        ob[10240 + n] = e5 * inv;
    }
}

__global__ __launch_bounds__(256) void k_reg_fb(
    const float* __restrict__ x, const float* __restrict__ A,
    float* __restrict__ out)
{
    const int p = blockIdx.x;
    const int b = blockIdx.y;
    int ci = 0, rem = p;
    while (rem >= 8 - ci) { rem -= 8 - ci; ++ci; }
    const int cj = ci + rem;
    const int t = threadIdx.x;
    __shared__ float4 pj[256];
    __shared__ float4 aj[256];
    const float* xb = x + (size_t)b * 12288;
    {
        int j = cj * 256 + t;
        pj[t] = make_float4(xb[j], xb[2048 + j], xb[4096 + j], 0.f);
        aj[t] = make_float4(A[j], A[2048 + j], A[4096 + j], 0.f);
    }
    __syncthreads();
    const int i = ci * 256 + t;
    const float pix = xb[i], piy = xb[2048 + i], piz = xb[4096 + i];
    const float aix = A[i], aiy = A[2048 + i], aiz = A[4096 + i];
    const int jbase = cj * 256;
    float acc = 0.f;
    #pragma unroll 4
    for (int jj = 0; jj < 256; ++jj) {
        float4 P = pj[jj];
        float4 Q = aj[jj];
        float dx0 = pix - P.x, dy0 = piy - P.y, dz0 = piz - P.z;
        float dxv = sqrtf(dx0 * dx0 + dy0 * dy0 + dz0 * dz0);
        float da0 = aix - Q.x, da1 = aiy - Q.y, da2 = aiz - Q.z;
        float dav = sqrtf(da0 * da0 + da1 * da1 + da2 * da2);
        float d = dav - dxv;
        float dd = (jbase + jj > i) ? d : 0.f;
        acc = fmaf(dd, dd, acc);
    }
    #pragma unroll
    for (int m = 1; m < 64; m <<= 1) acc += __shfl_xor(acc, m);
    __shared__ float wsum[4];
    if ((t & 63) == 0) wsum[t >> 6] = acc;
    __syncthreads();
    if (t == 0) atomicAdd(&out[REG_BASE + b], wsum[0] + wsum[1] + wsum[2] + wsum[3]);
}

__global__ void k_final_fb(float* __restrict__ out)
{
    int b = threadIdx.x;
    if (b < BATCH) out[REG_BASE + b] = sqrtf(2.f * out[REG_BASE + b]);
}

// ===========================================================================
extern "C" void kernel_launch(void* const* d_in, const int* in_sizes, int n_in,
                              void* d_out, int out_size, void* d_ws, size_t ws_size,
                              hipStream_t stream) {
    (void)in_sizes; (void)n_in; (void)out_size;
    const float* x      = (const float*)d_in[0];
    const float* W1     = (const float*)d_in[1];
    const float* b1     = (const float*)d_in[2];
    const float* W2     = (const float*)d_in[3];
    const float* b2     = (const float*)d_in[4];
    const float* A      = (const float*)d_in[5];
    const float* center = (const float*)d_in[6];
    const float* sz     = (const float*)d_in[7];
    float* out = (float*)d_out;
    float* ws  = (float*)d_ws;

    if (ws_size >= WS_BYTES) {
        k_h<<<dim3(4, 16), 256, 0, stream>>>(x, W1, b1, ws);
        k_transform<<<dim3(8, 17), 256, 0, stream>>>(x, A, W2, b2, center, sz, out, ws);
        k_cross<<<CBLKS, 256, 0, stream>>>(ws, out);
        k_final<<<16, 256, 0, stream>>>(ws, out);
    } else {
        k_mlp_fb<<<BATCH, 256, 0, stream>>>(x, W1, b1, W2, b2, center, sz, out);
        k_reg_fb<<<dim3(36, 16), 256, 0, stream>>>(x, A, out);
        k_final_fb<<<1, 64, 0, stream>>>(out);
    }
}